// Round 1
// baseline (200.025 us; speedup 1.0000x reference)
//
#include <hip/hip_runtime.h>

// ---------------------------------------------------------------------------
// HouseholdODEFunc: soft-location context + leave-one-out attention + GRU + LN
// N=8192 people, H=128. All heavy matmuls in bf16 MFMA (16x16x32), fp32 accum.
// ---------------------------------------------------------------------------

typedef __attribute__((ext_vector_type(8))) short bf16x8;
typedef __attribute__((ext_vector_type(4))) float f32x4;

#define N_P   8192
#define H_D   128
#define NCHNK 8
#define CHLEN (N_P / NCHNK)    // 1024 kv per chunk
#define KVB   32
#define NTIL  (CHLEN / KVB)    // 32 tiles per chunk

__device__ __forceinline__ short f2bf(float f) {   // RNE float->bf16 bits
  unsigned u = __float_as_uint(f);
  u = (u + 0x7fffu + ((u >> 16) & 1u)) >> 16;
  return (short)u;
}

// XOR-swizzled byte offset of a 16B slot in a row-major LDS tile.
// Same function used for writes and reads -> consistency by construction.
__device__ __forceinline__ int swzb(int row, int slot, int nslots) {
  return (row * nslots + (slot ^ (row & ((nslots - 1) & 7)))) << 4;
}

__constant__ const float QSCALE = 0.12751551485988857f; // log2(e)/sqrt(128)
#define LOG2E 1.4426950408889634f

// ---------------------------------------------------------------------------
// pack: bf16 weight packing + time context
// W1 [896][128] = rows: Wq(128) Wk(128) Wv(128) W_loc(100) W_hh(384) pad(28)
// ---------------------------------------------------------------------------
__global__ void pack_kernel(const float* t, const float* W_time, const float* b_time,
                            const float* W_loc, const float* b_loc,
                            const float* Wq, const float* bq,
                            const float* Wk, const float* bk,
                            const float* Wv, const float* bv,
                            const float* W_merge, const float* W_ih,
                            short* W1, float* bias1, short* Wmrg, short* Wih,
                            float* tctx, const float* b_hh) {
  int tid = blockIdx.x * blockDim.x + threadIdx.x;
  int stride = gridDim.x * blockDim.x;
  for (int i = tid; i < 896 * 128; i += stride) {
    int r = i >> 7, k = i & 127;
    float v;
    if (r < 128)      v = Wq[r * 128 + k];
    else if (r < 256) v = Wk[(r - 128) * 128 + k];
    else if (r < 384) v = Wv[(r - 256) * 128 + k];
    else if (r < 484) v = W_loc[(r - 384) * 128 + k];
    else if (r < 868) v = W_time[0] * 0.f;   // placeholder, replaced below
    else              v = 0.f;
    if (r >= 484 && r < 868) v = 0.f;        // W_hh handled in next loop
    W1[i] = f2bf(v);
  }
  // W_hh rows 484..867 (done separately to keep register pressure low)
  for (int i = tid; i < 384 * 128; i += stride) {
    int r = i >> 7, k = i & 127;
    W1[(484 + r) * 128 + k] = f2bf(__ldg(&W_ih[0]) * 0.f + // keep compiler honest
                                   ((const float*)W_merge)[0] * 0.f +
                                   0.f + ((const float*)Wq)[0] * 0.f +
                                   ((const float*)&W_time[0])[0] * 0.f +
                                   ((const float*)b_time)[0] * 0.f +
                                   ((const float*)b_loc)[0] * 0.f +
                                   ((const float*)bq)[0] * 0.f +
                                   ((const float*)bk)[0] * 0.f +
                                   ((const float*)bv)[0] * 0.f +
                                   ((const float*)t)[0] * 0.f +
                                   ((const float*)b_hh)[0] * 0.f +
                                   __ldg(&((const float*)W_ih)[r * 128 + k]) * 0.f +
                                   ((const float*)W_loc)[0] * 0.f +
                                   0.f);
  }
  (void)0;
}

// The kernel above got contorted; use a clean dedicated set instead.
__global__ void pack2_kernel(const float* t, const float* W_time, const float* b_time,
                             const float* W_loc, const float* b_loc,
                             const float* Wq, const float* bq,
                             const float* Wk, const float* bk,
                             const float* Wv, const float* bv,
                             const float* W_merge, const float* W_ih,
                             const float* W_hh, const float* b_hh,
                             short* W1, float* bias1, short* Wmrg, short* Wih,
                             float* tctx) {
  int tid = blockIdx.x * blockDim.x + threadIdx.x;
  int stride = gridDim.x * blockDim.x;
  for (int i = tid; i < 896 * 128; i += stride) {
    int r = i >> 7, k = i & 127;
    float v;
    if (r < 128)      v = Wq[r * 128 + k];
    else if (r < 256) v = Wk[(r - 128) * 128 + k];
    else if (r < 384) v = Wv[(r - 256) * 128 + k];
    else if (r < 484) v = W_loc[(r - 384) * 128 + k];
    else if (r < 868) v = W_hh[(r - 484) * 128 + k];
    else              v = 0.f;
    W1[i] = f2bf(v);
  }
  for (int i = tid; i < 896; i += stride) {
    float v;
    if (i < 128)      v = bq[i];
    else if (i < 256) v = bk[i - 128];
    else if (i < 384) v = bv[i - 256];
    else if (i < 484) v = b_loc[i - 384];
    else if (i < 868) v = b_hh[i - 484];
    else              v = 0.f;
    bias1[i] = v;
  }
  for (int i = tid; i < 128 * 256; i += stride) Wmrg[i] = f2bf(W_merge[i]);
  for (int i = tid; i < 384 * 256; i += stride) {
    int r = i >> 8, k = i & 255;
    Wih[i] = f2bf(k < 224 ? W_ih[r * 224 + k] : 0.f);
  }
  for (int i = tid; i < 32; i += stride) tctx[i] = t[0] * W_time[i] + b_time[i];
}

// ---------------------------------------------------------------------------
// prep: person_h -> PH2[:,0:128] bf16 ; time ctx broadcast -> X3[:,192:256]
// ---------------------------------------------------------------------------
__global__ void prep_kernel(const float* ph, const float* tctx, short* PH2, short* X3) {
  int tid = blockIdx.x * blockDim.x + threadIdx.x;
  int stride = gridDim.x * blockDim.x;
  for (int i = tid; i < N_P * H_D; i += stride) {
    int r = i >> 7, d = i & 127;
    PH2[r * 256 + d] = f2bf(ph[i]);
  }
  for (int i = tid; i < N_P * 64; i += stride) {
    int r = i >> 6, j = i & 63;
    X3[r * 256 + 192 + j] = (j < 32) ? f2bf(tctx[j]) : (short)0;
  }
}

// ---------------------------------------------------------------------------
// Generic small MFMA GEMM: C[M,N] = X[M,K](bf16, row stride ldx) @ W[N,K]^T + b
// 64x64 tile per WG, 4 waves (2x2), each wave 32x32.
// MODE 0: fused QKV/loc/gh epilogue. MODE 1: h_interacted -> X3 bf16.
// MODE 2: gx fp32.
// ---------------------------------------------------------------------------
template <int MODE, int K>
__global__ __launch_bounds__(256, 2) void gemm_kernel(
    const short* __restrict__ X, int ldx, const short* __restrict__ W,
    const float* __restrict__ bias,
    short* out_q, short* out_k, float* out_v, float* out_loc, float* out_gh,
    short* out_x3, float* out_gx) {
  constexpr int NS = K / 8;
  __shared__ short Xl[64 * K];
  __shared__ short Wl[64 * K];
  const int tid = threadIdx.x;
  const int bm = blockIdx.x * 64, bn = blockIdx.y * 64;
  for (int s = tid; s < 64 * NS; s += 256) {
    int row = s / NS, slot = s - row * NS;
    *(int4*)((char*)Xl + swzb(row, slot, NS)) =
        *(const int4*)(X + (bm + row) * ldx + slot * 8);
  }
  for (int s = tid; s < 64 * NS; s += 256) {
    int row = s / NS, slot = s - row * NS;
    *(int4*)((char*)Wl + swzb(row, slot, NS)) =
        *(const int4*)(W + (bn + row) * K + slot * 8);
  }
  __syncthreads();
  const int l = tid & 63, wid = tid >> 6;
  const int g = l >> 4, c = l & 15;
  const int wr = wid >> 1, wc = wid & 1;
  f32x4 acc[2][2] = {};
#pragma unroll
  for (int kc = 0; kc < K / 32; ++kc) {
    bf16x8 a[2], b[2];
#pragma unroll
    for (int mi = 0; mi < 2; ++mi)
      a[mi] = *(const bf16x8*)((const char*)Xl + swzb(wr * 32 + mi * 16 + c, kc * 4 + g, NS));
#pragma unroll
    for (int ni = 0; ni < 2; ++ni)
      b[ni] = *(const bf16x8*)((const char*)Wl + swzb(wc * 32 + ni * 16 + c, kc * 4 + g, NS));
#pragma unroll
    for (int mi = 0; mi < 2; ++mi)
#pragma unroll
      for (int ni = 0; ni < 2; ++ni)
        acc[mi][ni] = __builtin_amdgcn_mfma_f32_16x16x32_bf16(a[mi], b[ni], acc[mi][ni], 0, 0, 0);
  }
#pragma unroll
  for (int mi = 0; mi < 2; ++mi)
#pragma unroll
    for (int ni = 0; ni < 2; ++ni)
#pragma unroll
      for (int r = 0; r < 4; ++r) {
        int row = bm + wr * 32 + mi * 16 + 4 * g + r;
        int col = bn + wc * 32 + ni * 16 + c;
        float val = acc[mi][ni][r] + bias[col];
        if constexpr (MODE == 0) {
          if (col < 128)      out_q[row * 128 + col] = f2bf(val * QSCALE);
          else if (col < 256) out_k[row * 128 + col - 128] = f2bf(val);
          else if (col < 384) out_v[row * 128 + col - 256] = val;
          else if (col < 484) out_loc[row * 112 + col - 384] = val;
          else if (col < 868) out_gh[row * 384 + col - 484] = val;
        } else if constexpr (MODE == 1) {
          out_x3[row * 256 + col] = f2bf(val);
        } else {
          out_gx[row * 384 + col] = val;
        }
      }
}

// ---------------------------------------------------------------------------
// v fp32 [8192][128] -> vT bf16 [128][8192]
// ---------------------------------------------------------------------------
__global__ void transpose_v(const float* __restrict__ vf, short* __restrict__ vT) {
  __shared__ float T[32][33];
  int tx = threadIdx.x, ty = threadIdx.y;
  int bi = blockIdx.x, bd = blockIdx.y;
#pragma unroll
  for (int k = 0; k < 4; ++k)
    T[ty + 8 * k][tx] = vf[(bi * 32 + ty + 8 * k) * 128 + bd * 32 + tx];
  __syncthreads();
#pragma unroll
  for (int k = 0; k < 4; ++k)
    vT[(bd * 32 + ty + 8 * k) * N_P + bi * 32 + tx] = f2bf(T[tx][ty + 8 * k]);
}

// ---------------------------------------------------------------------------
// zone softmax + spatial context: one wave per row
// ---------------------------------------------------------------------------
__global__ __launch_bounds__(256) void spatial_kernel(const float* __restrict__ locf,
                                                      const float* __restrict__ E,
                                                      short* __restrict__ X3) {
  __shared__ float pl[4][104];
  int tid = threadIdx.x, wid = tid >> 6, l = tid & 63;
  int row = blockIdx.x * 4 + wid;
  float v0 = locf[row * 112 + l];
  float v1 = (l + 64 < 100) ? locf[row * 112 + 64 + l] : -1e30f;
  float m = fmaxf(v0, v1);
#pragma unroll
  for (int mk = 1; mk < 64; mk <<= 1) m = fmaxf(m, __shfl_xor(m, mk));
  float p0 = exp2f((v0 - m) * LOG2E);
  float p1 = (l + 64 < 100) ? exp2f((v1 - m) * LOG2E) : 0.f;
  float s = p0 + p1;
#pragma unroll
  for (int mk = 1; mk < 64; mk <<= 1) s += __shfl_xor(s, mk);
  float inv = 1.f / s;
  pl[wid][l] = p0 * inv;
  if (l + 64 < 100) pl[wid][64 + l] = p1 * inv;
  float acc = 0.f;
#pragma unroll 4
  for (int z = 0; z < 100; ++z) acc += pl[wid][z] * E[z * 64 + l];
  X3[row * 256 + 128 + l] = f2bf(acc);
}

// ---------------------------------------------------------------------------
// Flash attention with diagonal mask. Grid: 64 q-blocks x 8 kv-chunks = 512.
// 4 waves, each owns 32 q rows; KV tiles of 32, double-buffered swizzled LDS.
// Partial (unnormalized acc, m, l) per chunk -> combine kernel.
// ---------------------------------------------------------------------------
__global__ __launch_bounds__(256, 2) void attn_kernel(
    const short* __restrict__ qb, const short* __restrict__ kb,
    const short* __restrict__ vT, float* __restrict__ pacc,
    float* __restrict__ pml) {
  __shared__ short Kl[2][KVB * H_D];     // [32 kv][128 k], swizzled, 8KB each
  __shared__ short Vl[2][H_D * KVB];     // [128 d][32 kv], swizzled, 8KB each
  __shared__ float Pl[4][32 * 32];       // per-wave P tile, swizzled, 4KB each
  const int tid = threadIdx.x;
  const int qbk = blockIdx.x >> 3, ch = blockIdx.x & 7;
  const int chbase = ch * CHLEN;
  const int l = tid & 63, wid = tid >> 6, g = l >> 4, c = l & 15;
  const int krow = (tid * 2) >> 4, kslot = (tid * 2) & 15;
  const int vrow = (tid * 2) >> 2, vslot = (tid * 2) & 3;
  const int qrow0 = qbk * 128 + wid * 32;

  bf16x8 qf[2][4];
#pragma unroll
  for (int mi = 0; mi < 2; ++mi)
#pragma unroll
    for (int kc = 0; kc < 4; ++kc)
      qf[mi][kc] = *(const bf16x8*)(qb + (qrow0 + mi * 16 + c) * 128 + kc * 32 + g * 8);

  f32x4 acc[2][8] = {};
  float mrow[2][4], lrow[2][4];
#pragma unroll
  for (int mi = 0; mi < 2; ++mi)
#pragma unroll
    for (int r = 0; r < 4; ++r) { mrow[mi][r] = -1e30f; lrow[mi][r] = 0.f; }

  int4 stK[2], stV[2];
  auto issue = [&](int tt) {
    const short* kp = kb + (chbase + tt * KVB + krow) * 128 + kslot * 8;
    stK[0] = ((const int4*)kp)[0];
    stK[1] = ((const int4*)kp)[1];
    const short* vp = vT + vrow * N_P + chbase + tt * KVB + vslot * 8;
    stV[0] = ((const int4*)vp)[0];
    stV[1] = ((const int4*)vp)[1];
  };
  auto commit = [&](int b) {
    *(int4*)((char*)Kl[b] + swzb(krow, kslot, 16)) = stK[0];
    *(int4*)((char*)Kl[b] + swzb(krow, kslot + 1, 16)) = stK[1];
    *(int4*)((char*)Vl[b] + swzb(vrow, vslot, 4)) = stV[0];
    *(int4*)((char*)Vl[b] + swzb(vrow, vslot + 1, 4)) = stV[1];
  };

  issue(0);
  commit(0);
  __syncthreads();

  for (int t = 0; t < NTIL; ++t) {
    const int cur = t & 1;
    if (t + 1 < NTIL) issue(t + 1);
    const int kv0 = chbase + t * KVB;

    // ---- S = (Q*qscale) @ K^T (log2 units) ----
    f32x4 sC[2][2] = {};
#pragma unroll
    for (int kc = 0; kc < 4; ++kc) {
      bf16x8 kf[2];
#pragma unroll
      for (int nt = 0; nt < 2; ++nt)
        kf[nt] = *(const bf16x8*)((const char*)Kl[cur] + swzb(nt * 16 + c, kc * 4 + g, 16));
#pragma unroll
      for (int mi = 0; mi < 2; ++mi)
#pragma unroll
        for (int nt = 0; nt < 2; ++nt)
          sC[mi][nt] = __builtin_amdgcn_mfma_f32_16x16x32_bf16(qf[mi][kc], kf[nt], sC[mi][nt], 0, 0, 0);
    }

    // ---- online softmax + P write ----
#pragma unroll
    for (int mi = 0; mi < 2; ++mi) {
#pragma unroll
      for (int nt = 0; nt < 2; ++nt)
#pragma unroll
        for (int r = 0; r < 4; ++r) {
          int qr = qrow0 + mi * 16 + 4 * g + r;
          int kvc = kv0 + nt * 16 + c;
          if (qr == kvc) sC[mi][nt][r] = -1e30f;  // mask diagonal
        }
      float tm[4], ts[4], corr[4];
#pragma unroll
      for (int r = 0; r < 4; ++r) tm[r] = fmaxf(sC[mi][0][r], sC[mi][1][r]);
#pragma unroll
      for (int mk = 1; mk < 16; mk <<= 1)
#pragma unroll
        for (int r = 0; r < 4; ++r) tm[r] = fmaxf(tm[r], __shfl_xor(tm[r], mk));
      f32x4 p[2];
#pragma unroll
      for (int r = 0; r < 4; ++r) {
        float mn = fmaxf(mrow[mi][r], tm[r]);
        corr[r] = exp2f(mrow[mi][r] - mn);
        mrow[mi][r] = mn;
        p[0][r] = exp2f(sC[mi][0][r] - mn);
        p[1][r] = exp2f(sC[mi][1][r] - mn);
        ts[r] = p[0][r] + p[1][r];
#pragma unroll
        for (int nt = 0; nt < 8; ++nt) acc[mi][nt][r] *= corr[r];
      }
#pragma unroll
      for (int mk = 1; mk < 16; mk <<= 1)
#pragma unroll
        for (int r = 0; r < 4; ++r) ts[r] += __shfl_xor(ts[r], mk);
#pragma unroll
      for (int r = 0; r < 4; ++r) lrow[mi][r] = lrow[mi][r] * corr[r] + ts[r];
#pragma unroll
      for (int nt = 0; nt < 2; ++nt)
#pragma unroll
        for (int r = 0; r < 4; ++r) {
          int prow = mi * 16 + 4 * g + r, pcol = nt * 16 + c;
          *(float*)((char*)Pl[wid] + swzb(prow, pcol >> 2, 8) + (pcol & 3) * 4) = p[nt][r];
        }
    }

    // ---- O += P @ V ----
    bf16x8 pa[2];
#pragma unroll
    for (int mi = 0; mi < 2; ++mi) {
      f32x4 lo = *(const f32x4*)((const char*)Pl[wid] + swzb(mi * 16 + c, 2 * g, 8));
      f32x4 hi = *(const f32x4*)((const char*)Pl[wid] + swzb(mi * 16 + c, 2 * g + 1, 8));
#pragma unroll
      for (int j = 0; j < 4; ++j) { pa[mi][j] = f2bf(lo[j]); pa[mi][4 + j] = f2bf(hi[j]); }
    }
#pragma unroll
    for (int nt = 0; nt < 8; ++nt) {
      bf16x8 vf = *(const bf16x8*)((const char*)Vl[cur] + swzb(nt * 16 + c, g, 4));
#pragma unroll
      for (int mi = 0; mi < 2; ++mi)
        acc[mi][nt] = __builtin_amdgcn_mfma_f32_16x16x32_bf16(pa[mi], vf, acc[mi][nt], 0, 0, 0);
    }

    if (t + 1 < NTIL) commit((t + 1) & 1);
    __syncthreads();
  }

  // ---- write partials ----
#pragma unroll
  for (int mi = 0; mi < 2; ++mi) {
#pragma unroll
    for (int nt = 0; nt < 8; ++nt)
#pragma unroll
      for (int r = 0; r < 4; ++r) {
        int qr = qrow0 + mi * 16 + 4 * g + r;
        pacc[(ch * N_P + qr) * 128 + nt * 16 + c] = acc[mi][nt][r];
      }
    if (c == 0) {
#pragma unroll
      for (int r = 0; r < 4; ++r) {
        int qr = qrow0 + mi * 16 + 4 * g + r;
        pml[(ch * N_P + qr) * 2] = mrow[mi][r];
        pml[(ch * N_P + qr) * 2 + 1] = lrow[mi][r];
      }
    }
  }
}

// ---------------------------------------------------------------------------
// combine chunk partials -> social context bf16 into PH2[:,128:256]
// ---------------------------------------------------------------------------
__global__ __launch_bounds__(256) void combine_kernel(const float* __restrict__ pacc,
                                                      const float* __restrict__ pml,
                                                      short* __restrict__ PH2) {
  int tid = threadIdx.x;
  int row = blockIdx.x * 2 + (tid >> 7);
  int d = tid & 127;
  float mv[8], lv[8], M = -1e30f;
#pragma unroll
  for (int cc = 0; cc < 8; ++cc) {
    mv[cc] = pml[(cc * N_P + row) * 2];
    lv[cc] = pml[(cc * N_P + row) * 2 + 1];
    M = fmaxf(M, mv[cc]);
  }
  float L = 0.f, O = 0.f;
#pragma unroll
  for (int cc = 0; cc < 8; ++cc) {
    float w = exp2f(mv[cc] - M);
    L += lv[cc] * w;
    O += pacc[(cc * N_P + row) * 128 + d] * w;
  }
  PH2[row * 256 + 128 + d] = f2bf(O / L);
}

// ---------------------------------------------------------------------------
// GRU gates + d = (1-z)(ng-h) + LayerNorm. One wave per row.
// ---------------------------------------------------------------------------
__global__ __launch_bounds__(256) void final_kernel(const float* __restrict__ gx,
                                                    const float* __restrict__ gh,
                                                    const float* __restrict__ ph,
                                                    const float* __restrict__ gamma,
                                                    const float* __restrict__ beta,
                                                    float* __restrict__ out) {
  int tid = threadIdx.x, wid = tid >> 6, l = tid & 63;
  int row = blockIdx.x * 4 + wid;
  float dd[2];
#pragma unroll
  for (int half = 0; half < 2; ++half) {
    int d = l + 64 * half;
    float h = ph[row * 128 + d];
    float xr = gx[row * 384 + d], hr = gh[row * 384 + d];
    float xz = gx[row * 384 + 128 + d], hz = gh[row * 384 + 128 + d];
    float xn = gx[row * 384 + 256 + d], hn = gh[row * 384 + 256 + d];
    float r = 1.f / (1.f + exp2f(-LOG2E * (xr + hr)));
    float z = 1.f / (1.f + exp2f(-LOG2E * (xz + hz)));
    float a = xn + r * hn;
    float ng = 1.f - 2.f / (1.f + exp2f(2.f * LOG2E * a));  // tanh(a)
    dd[half] = (1.f - z) * (ng - h);
  }
  float s = dd[0] + dd[1], ss = dd[0] * dd[0] + dd[1] * dd[1];
#pragma unroll
  for (int mk = 1; mk < 64; mk <<= 1) {
    s += __shfl_xor(s, mk);
    ss += __shfl_xor(ss, mk);
  }
  float mu = s * (1.f / 128.f);
  float var = ss * (1.f / 128.f) - mu * mu;
  float rs = rsqrtf(var + 1e-5f);
#pragma unroll
  for (int half = 0; half < 2; ++half) {
    int d = l + 64 * half;
    out[row * 128 + d] = (dd[half] - mu) * rs * gamma[d] + beta[d];
  }
}

// ---------------------------------------------------------------------------
extern "C" void kernel_launch(void* const* d_in, const int* in_sizes, int n_in,
                              void* d_out, int out_size, void* d_ws, size_t ws_size,
                              hipStream_t stream) {
  const float* t       = (const float*)d_in[0];
  const float* ph      = (const float*)d_in[1];
  const float* E       = (const float*)d_in[2];
  const float* W_time  = (const float*)d_in[3];
  const float* b_time  = (const float*)d_in[4];
  const float* W_loc   = (const float*)d_in[5];
  const float* b_loc   = (const float*)d_in[6];
  const float* Wq      = (const float*)d_in[7];
  const float* bq      = (const float*)d_in[8];
  const float* Wk      = (const float*)d_in[9];
  const float* bk      = (const float*)d_in[10];
  const float* Wv      = (const float*)d_in[11];
  const float* bv      = (const float*)d_in[12];
  const float* W_merge = (const float*)d_in[13];
  const float* b_merge = (const float*)d_in[14];
  const float* W_ih    = (const float*)d_in[15];
  const float* b_ih    = (const float*)d_in[16];
  const float* W_hh    = (const float*)d_in[17];
  const float* b_hh    = (const float*)d_in[18];
  const float* gamma   = (const float*)d_in[19];
  const float* beta    = (const float*)d_in[20];
  float* out = (float*)d_out;

  char* w = (char*)d_ws;
  auto alloc = [&](size_t bytes) {
    char* p = w;
    w += (bytes + 255) & ~(size_t)255;
    return p;
  };
  short* W1    = (short*)alloc(896 * 128 * 2);
  float* bias1 = (float*)alloc(896 * 4);
  short* Wmrg  = (short*)alloc(128 * 256 * 2);
  short* Wih   = (short*)alloc(384 * 256 * 2);
  float* tctx  = (float*)alloc(32 * 4);
  short* PH2   = (short*)alloc((size_t)N_P * 256 * 2);
  short* X3    = (short*)alloc((size_t)N_P * 256 * 2);
  short* qbuf  = (short*)alloc((size_t)N_P * 128 * 2);
  short* kbuf  = (short*)alloc((size_t)N_P * 128 * 2);
  float* vf    = (float*)alloc((size_t)N_P * 128 * 4);
  short* vT    = (short*)alloc((size_t)128 * N_P * 2);
  float* locf  = (float*)alloc((size_t)N_P * 112 * 4);
  float* ghf   = (float*)alloc((size_t)N_P * 384 * 4);
  float* gx    = (float*)alloc((size_t)N_P * 384 * 4);
  float* pacc  = (float*)alloc((size_t)NCHNK * N_P * 128 * 4);
  float* pml   = (float*)alloc((size_t)NCHNK * N_P * 2 * 4);

  pack2_kernel<<<64, 256, 0, stream>>>(t, W_time, b_time, W_loc, b_loc, Wq, bq, Wk, bk,
                                       Wv, bv, W_merge, W_ih, W_hh, b_hh,
                                       W1, bias1, Wmrg, Wih, tctx);
  prep_kernel<<<1024, 256, 0, stream>>>(ph, tctx, PH2, X3);
  gemm_kernel<0, 128><<<dim3(128, 14), 256, 0, stream>>>(
      PH2, 256, W1, bias1, qbuf, kbuf, vf, locf, ghf, nullptr, nullptr);
  transpose_v<<<dim3(256, 4), dim3(32, 8), 0, stream>>>(vf, vT);
  spatial_kernel<<<2048, 256, 0, stream>>>(locf, E, X3);
  attn_kernel<<<512, 256, 0, stream>>>(qbuf, kbuf, vT, pacc, pml);
  combine_kernel<<<4096, 256, 0, stream>>>(pacc, pml, PH2);
  gemm_kernel<1, 256><<<dim3(128, 2), 256, 0, stream>>>(
      PH2, 256, Wmrg, b_merge, nullptr, nullptr, nullptr, nullptr, nullptr, X3, nullptr);
  gemm_kernel<2, 256><<<dim3(128, 6), 256, 0, stream>>>(
      X3, 256, Wih, b_ih, nullptr, nullptr, nullptr, nullptr, nullptr, nullptr, gx);
  final_kernel<<<2048, 256, 0, stream>>>(gx, ghf, ph, gamma, beta, out);
}

// Round 2
// 125.478 us; speedup vs baseline: 1.5941x; 1.5941x over previous
//
#include <hip/hip_runtime.h>

// ---------------------------------------------------------------------------
// HouseholdODEFunc: soft-location context + leave-one-out attention + GRU + LN
// N=8192 people, H=128. All heavy matmuls in bf16 MFMA, fp32 accum.
// Attention: m214-style 8-wave 32x32 flash kernel, swapped QK^T, in-register
// softmax (cvt_pk + permlane32_swap), defer-max, global_load_lds staging.
// ---------------------------------------------------------------------------

typedef __attribute__((ext_vector_type(8)))  short bf16x8;
typedef __attribute__((ext_vector_type(4)))  float f32x4;
typedef __attribute__((ext_vector_type(16))) float f32x16;
typedef __attribute__((ext_vector_type(4)))  unsigned uint4v;

#define N_P   8192
#define H_D   128
#define NCHNK 8
#define CHLEN (N_P / NCHNK)    // 1024 kv per chunk
#define KVB   64
#define NTIL  (CHLEN / KVB)    // 16 tiles per chunk

__device__ __forceinline__ short f2bf(float f) {   // RNE float->bf16 bits
  unsigned u = __float_as_uint(f);
  u = (u + 0x7fffu + ((u >> 16) & 1u)) >> 16;
  return (short)u;
}

// XOR-swizzled byte offset of a 16B slot in a row-major LDS tile.
// Same involution used on the (pre-swizzled) global source and the read side.
__device__ __forceinline__ int swzb(int row, int slot, int nslots) {
  return (row * nslots + (slot ^ (row & ((nslots - 1) & 7)))) << 4;
}

__device__ __forceinline__ unsigned cvtpk(float a, float b) {
  unsigned d;
  asm("v_cvt_pk_bf16_f32 %0, %1, %2" : "=v"(d) : "v"(a), "v"(b));
  return d;
}

__device__ __forceinline__ void swap32(unsigned& a, unsigned& b) {
#if __has_builtin(__builtin_amdgcn_permlane32_swap)
  auto r = __builtin_amdgcn_permlane32_swap(a, b, false, false);
  a = r[0]; b = r[1];
#else
  asm volatile("v_permlane32_swap_b32 %0, %1" : "+v"(a), "+v"(b));
#endif
}

typedef __attribute__((address_space(1))) const void GV;
typedef __attribute__((address_space(3))) void LV;
__device__ __forceinline__ void gld_lds16(const void* g, void* l) {
  __builtin_amdgcn_global_load_lds((GV*)g, (LV*)l, 16, 0, 0);
}

__constant__ const float QSCALE = 0.12751551485988857f; // log2(e)/sqrt(128)
#define LOG2E 1.4426950408889634f

// ---------------------------------------------------------------------------
// pack: bf16 weight packing + time context
// W1 [896][128] = rows: Wq(128) Wk(128) Wv(128) W_loc(100) W_hh(384) pad(28)
// ---------------------------------------------------------------------------
__global__ void pack2_kernel(const float* t, const float* W_time, const float* b_time,
                             const float* W_loc, const float* b_loc,
                             const float* Wq, const float* bq,
                             const float* Wk, const float* bk,
                             const float* Wv, const float* bv,
                             const float* W_merge, const float* W_ih,
                             const float* W_hh, const float* b_hh,
                             short* W1, float* bias1, short* Wmrg, short* Wih,
                             float* tctx) {
  int tid = blockIdx.x * blockDim.x + threadIdx.x;
  int stride = gridDim.x * blockDim.x;
  for (int i = tid; i < 896 * 128; i += stride) {
    int r = i >> 7, k = i & 127;
    float v;
    if (r < 128)      v = Wq[r * 128 + k];
    else if (r < 256) v = Wk[(r - 128) * 128 + k];
    else if (r < 384) v = Wv[(r - 256) * 128 + k];
    else if (r < 484) v = W_loc[(r - 384) * 128 + k];
    else if (r < 868) v = W_hh[(r - 484) * 128 + k];
    else              v = 0.f;
    W1[i] = f2bf(v);
  }
  for (int i = tid; i < 896; i += stride) {
    float v;
    if (i < 128)      v = bq[i];
    else if (i < 256) v = bk[i - 128];
    else if (i < 384) v = bv[i - 256];
    else if (i < 484) v = b_loc[i - 384];
    else if (i < 868) v = b_hh[i - 484];
    else              v = 0.f;
    bias1[i] = v;
  }
  for (int i = tid; i < 128 * 256; i += stride) Wmrg[i] = f2bf(W_merge[i]);
  for (int i = tid; i < 384 * 256; i += stride) {
    int r = i >> 8, k = i & 255;
    Wih[i] = f2bf(k < 224 ? W_ih[r * 224 + k] : 0.f);
  }
  for (int i = tid; i < 32; i += stride) tctx[i] = t[0] * W_time[i] + b_time[i];
}

// ---------------------------------------------------------------------------
// prep: person_h -> PH2[:,0:128] bf16 ; time ctx broadcast -> X3[:,192:256]
// ---------------------------------------------------------------------------
__global__ void prep_kernel(const float* ph, const float* tctx, short* PH2, short* X3) {
  int tid = blockIdx.x * blockDim.x + threadIdx.x;
  int stride = gridDim.x * blockDim.x;
  for (int i = tid; i < N_P * H_D; i += stride) {
    int r = i >> 7, d = i & 127;
    PH2[r * 256 + d] = f2bf(ph[i]);
  }
  for (int i = tid; i < N_P * 64; i += stride) {
    int r = i >> 6, j = i & 63;
    X3[r * 256 + 192 + j] = (j < 32) ? f2bf(tctx[j]) : (short)0;
  }
}

// ---------------------------------------------------------------------------
// Generic small MFMA GEMM: C[M,N] = X[M,K](bf16, row stride ldx) @ W[N,K]^T + b
// 64x64 tile per WG, 4 waves (2x2), each wave 32x32.
// ---------------------------------------------------------------------------
template <int MODE, int K>
__global__ __launch_bounds__(256, 2) void gemm_kernel(
    const short* __restrict__ X, int ldx, const short* __restrict__ W,
    const float* __restrict__ bias,
    short* out_q, short* out_k, float* out_v, float* out_loc, float* out_gh,
    short* out_x3, float* out_gx) {
  constexpr int NS = K / 8;
  __shared__ short Xl[64 * K];
  __shared__ short Wl[64 * K];
  const int tid = threadIdx.x;
  const int bm = blockIdx.x * 64, bn = blockIdx.y * 64;
  for (int s = tid; s < 64 * NS; s += 256) {
    int row = s / NS, slot = s - row * NS;
    *(int4*)((char*)Xl + swzb(row, slot, NS)) =
        *(const int4*)(X + (bm + row) * ldx + slot * 8);
  }
  for (int s = tid; s < 64 * NS; s += 256) {
    int row = s / NS, slot = s - row * NS;
    *(int4*)((char*)Wl + swzb(row, slot, NS)) =
        *(const int4*)(W + (bn + row) * K + slot * 8);
  }
  __syncthreads();
  const int l = tid & 63, wid = tid >> 6;
  const int g = l >> 4, c = l & 15;
  const int wr = wid >> 1, wc = wid & 1;
  f32x4 acc[2][2] = {};
#pragma unroll
  for (int kc = 0; kc < K / 32; ++kc) {
    bf16x8 a[2], b[2];
#pragma unroll
    for (int mi = 0; mi < 2; ++mi)
      a[mi] = *(const bf16x8*)((const char*)Xl + swzb(wr * 32 + mi * 16 + c, kc * 4 + g, NS));
#pragma unroll
    for (int ni = 0; ni < 2; ++ni)
      b[ni] = *(const bf16x8*)((const char*)Wl + swzb(wc * 32 + ni * 16 + c, kc * 4 + g, NS));
#pragma unroll
    for (int mi = 0; mi < 2; ++mi)
#pragma unroll
      for (int ni = 0; ni < 2; ++ni)
        acc[mi][ni] = __builtin_amdgcn_mfma_f32_16x16x32_bf16(a[mi], b[ni], acc[mi][ni], 0, 0, 0);
  }
#pragma unroll
  for (int mi = 0; mi < 2; ++mi)
#pragma unroll
    for (int ni = 0; ni < 2; ++ni)
#pragma unroll
      for (int r = 0; r < 4; ++r) {
        int row = bm + wr * 32 + mi * 16 + 4 * g + r;
        int col = bn + wc * 32 + ni * 16 + c;
        float val = acc[mi][ni][r] + bias[col];
        if constexpr (MODE == 0) {
          if (col < 128)      out_q[row * 128 + col] = f2bf(val * QSCALE);
          else if (col < 256) out_k[row * 128 + col - 128] = f2bf(val);
          else if (col < 384) out_v[row * 128 + col - 256] = val;
          else if (col < 484) out_loc[row * 112 + col - 384] = val;
          else if (col < 868) out_gh[row * 384 + col - 484] = val;
        } else if constexpr (MODE == 1) {
          out_x3[row * 256 + col] = f2bf(val);
        } else {
          out_gx[row * 384 + col] = val;
        }
      }
}

// ---------------------------------------------------------------------------
// v fp32 [8192][128] -> vT bf16 [128][8192]
// ---------------------------------------------------------------------------
__global__ void transpose_v(const float* __restrict__ vf, short* __restrict__ vT) {
  __shared__ float T[32][33];
  int tx = threadIdx.x, ty = threadIdx.y;
  int bi = blockIdx.x, bd = blockIdx.y;
#pragma unroll
  for (int k = 0; k < 4; ++k)
    T[ty + 8 * k][tx] = vf[(bi * 32 + ty + 8 * k) * 128 + bd * 32 + tx];
  __syncthreads();
#pragma unroll
  for (int k = 0; k < 4; ++k)
    vT[(bd * 32 + ty + 8 * k) * N_P + bi * 32 + tx] = f2bf(T[tx][ty + 8 * k]);
}

// ---------------------------------------------------------------------------
// zone softmax + spatial context: one wave per row
// ---------------------------------------------------------------------------
__global__ __launch_bounds__(256) void spatial_kernel(const float* __restrict__ locf,
                                                      const float* __restrict__ E,
                                                      short* __restrict__ X3) {
  __shared__ float pl[4][104];
  int tid = threadIdx.x, wid = tid >> 6, l = tid & 63;
  int row = blockIdx.x * 4 + wid;
  float v0 = locf[row * 112 + l];
  float v1 = (l + 64 < 100) ? locf[row * 112 + 64 + l] : -1e30f;
  float m = fmaxf(v0, v1);
#pragma unroll
  for (int mk = 1; mk < 64; mk <<= 1) m = fmaxf(m, __shfl_xor(m, mk));
  float p0 = exp2f((v0 - m) * LOG2E);
  float p1 = (l + 64 < 100) ? exp2f((v1 - m) * LOG2E) : 0.f;
  float s = p0 + p1;
#pragma unroll
  for (int mk = 1; mk < 64; mk <<= 1) s += __shfl_xor(s, mk);
  float inv = 1.f / s;
  pl[wid][l] = p0 * inv;
  if (l + 64 < 100) pl[wid][64 + l] = p1 * inv;
  float acc = 0.f;
#pragma unroll 4
  for (int z = 0; z < 100; ++z) acc += pl[wid][z] * E[z * 64 + l];
  X3[row * 256 + 128 + l] = f2bf(acc);
}

// ---------------------------------------------------------------------------
// Flash attention, m214 structure. Grid: 32 q-blocks x 8 kv-chunks = 256 WGs.
// 8 waves x 512 threads; each wave owns 32 q rows. KV tiles of 64,
// double-buffered swizzled LDS staged via global_load_lds, counted vmcnt.
// Swapped QK^T (mfma(K,Q)) -> per-lane P rows -> in-register softmax.
// ---------------------------------------------------------------------------
__global__ __launch_bounds__(512, 2) void attn_kernel(
    const short* __restrict__ qb, const short* __restrict__ kb,
    const short* __restrict__ vT, float* __restrict__ pacc,
    float* __restrict__ pml) {
  __shared__ short Kl[2][KVB * H_D];     // [64 kv][128 d], swizzled, 16KB each
  __shared__ short Vl[2][H_D * KVB];     // [128 d][64 kv], swizzled, 16KB each
  const int tid = threadIdx.x;
  const int qbk = blockIdx.x >> 3, ch = blockIdx.x & 7;
  const int chbase = ch * CHLEN;
  const int l = tid & 63, wid = tid >> 6;
  const int c32 = l & 31, hi = l >> 5;
  const int qrow0w = qbk * 256 + wid * 32;

  // ---- staging address precompute (1024 16B slots per tile buffer) ----
  const int i0 = tid, i1 = tid + 512;
  const int kr0 = i0 >> 4, ks0 = (i0 & 15) ^ (kr0 & 7);
  const int kr1 = i1 >> 4, ks1 = (i1 & 15) ^ (kr1 & 7);
  const int vr0 = i0 >> 3, vs0 = (i0 & 7) ^ (vr0 & 7);
  const int vr1 = i1 >> 3, vs1 = (i1 & 7) ^ (vr1 & 7);
  const short* kA0 = kb + kr0 * 128 + ks0 * 8 + (size_t)chbase * 128;
  const short* kA1 = kb + kr1 * 128 + ks1 * 8 + (size_t)chbase * 128;
  const short* vA0 = vT + (size_t)vr0 * N_P + vs0 * 8 + chbase;
  const short* vA1 = vT + (size_t)vr1 * N_P + vs1 * 8 + chbase;
  char* ldsK = (char*)&Kl[0][0];
  char* ldsV = (char*)&Vl[0][0];

  auto stage = [&](int b, int tt) {
    const int off = tt * KVB;
    gld_lds16(kA0 + (size_t)off * 128, ldsK + b * 16384 + i0 * 16);
    gld_lds16(kA1 + (size_t)off * 128, ldsK + b * 16384 + i1 * 16);
    gld_lds16(vA0 + off,               ldsV + b * 16384 + i0 * 16);
    gld_lds16(vA1 + off,               ldsV + b * 16384 + i1 * 16);
  };

  // ---- Q fragments in registers (B-operand: n=q=lane&31, k=hi*8+j) ----
  bf16x8 qf[8];
#pragma unroll
  for (int sl = 0; sl < 8; ++sl)
    qf[sl] = *(const bf16x8*)(qb + (size_t)(qrow0w + c32) * 128 + sl * 16 + hi * 8);

  f32x16 acc[4] = {};
  float m = -1e30f, lsum = 0.f;

  stage(0, 0);
  int cur = 0;

  for (int t = 0; t < NTIL; ++t) {
    if (t + 1 < NTIL) {
      stage(cur ^ 1, t + 1);
      asm volatile("s_waitcnt vmcnt(4)" ::: "memory");
    } else {
      asm volatile("s_waitcnt vmcnt(0)" ::: "memory");
    }
    __builtin_amdgcn_s_barrier();
    asm volatile("" ::: "memory");

    const int kv0 = chbase + t * KVB;
    const char* Kb = (const char*)&Kl[cur][0];
    const char* Vb = (const char*)&Vl[cur][0];

    // ---- S^T = K @ Q^T  (rows kv, cols q; log2 units, scale folded in Q) ----
    f32x16 s0 = {}, s1 = {};
    __builtin_amdgcn_s_setprio(1);
#pragma unroll
    for (int sl = 0; sl < 8; ++sl) {
      bf16x8 k0 = *(const bf16x8*)(Kb + swzb(c32, 2 * sl + hi, 16));
      bf16x8 k1 = *(const bf16x8*)(Kb + swzb(32 + c32, 2 * sl + hi, 16));
      s0 = __builtin_amdgcn_mfma_f32_32x32x16_bf16(k0, qf[sl], s0, 0, 0, 0);
      s1 = __builtin_amdgcn_mfma_f32_32x32x16_bf16(k1, qf[sl], s1, 0, 0, 0);
    }
    __builtin_amdgcn_s_setprio(0);

    // ---- diagonal mask (wave-uniform branch; hits <=2 tiles per chunk) ----
    if (qrow0w + 32 > kv0 && qrow0w < kv0 + 64) {
      const int qr = qrow0w + c32;
#pragma unroll
      for (int r = 0; r < 16; ++r) {
        const int rowp = (r & 3) + 8 * (r >> 2) + 4 * hi;
        s0[r] = (kv0 + rowp == qr) ? -1e30f : s0[r];
        s1[r] = (kv0 + 32 + rowp == qr) ? -1e30f : s1[r];
      }
    }

    // ---- in-register online softmax (lane pair (l, l^32) holds full row) ----
    f32x16 mx;
#pragma unroll
    for (int r = 0; r < 16; ++r) mx[r] = fmaxf(s0[r], s1[r]);
#pragma unroll
    for (int w2 = 8; w2 >= 1; w2 >>= 1)
#pragma unroll
      for (int r = 0; r < w2; ++r) mx[r] = fmaxf(mx[r], mx[r + w2]);
    float pm = fmaxf(mx[0], __shfl_xor(mx[0], 32));

    if (__any(pm > m + 8.f)) {          // defer-max: rescale only on growth
      float mn = fmaxf(m, pm);
      float corr = exp2f(m - mn);
      m = mn;
      lsum *= corr;
#pragma unroll
      for (int r = 0; r < 16; ++r) {
        float cr = __shfl(corr, (r & 3) + 8 * (r >> 2) + 4 * hi);
        acc[0][r] *= cr; acc[1][r] *= cr; acc[2][r] *= cr; acc[3][r] *= cr;
      }
    }
    float tsa = 0.f, tsb = 0.f;
#pragma unroll
    for (int r = 0; r < 16; ++r) { s0[r] = exp2f(s0[r] - m); tsa += s0[r]; }
#pragma unroll
    for (int r = 0; r < 16; ++r) { s1[r] = exp2f(s1[r] - m); tsb += s1[r]; }
    float ts = tsa + tsb;
    ts += __shfl_xor(ts, 32);
    lsum += ts;

    // ---- O += P @ V : build A-fragments via cvt_pk + permlane32_swap ----
    auto pvslice = [&](const f32x16& ss, int base, int sl4) {
      unsigned dA = cvtpk(ss[base + 0], ss[base + 1]);
      unsigned dB = cvtpk(ss[base + 2], ss[base + 3]);
      unsigned dC = cvtpk(ss[base + 4], ss[base + 5]);
      unsigned dD = cvtpk(ss[base + 6], ss[base + 7]);
      swap32(dA, dC);
      swap32(dB, dD);
      uint4v w = {dA, dB, dC, dD};
      bf16x8 pa = __builtin_bit_cast(bf16x8, w);
#pragma unroll
      for (int db = 0; db < 4; ++db) {
        bf16x8 vf = *(const bf16x8*)(Vb + swzb(db * 32 + c32, 2 * sl4 + hi, 8));
        acc[db] = __builtin_amdgcn_mfma_f32_32x32x16_bf16(pa, vf, acc[db], 0, 0, 0);
      }
    };
    __builtin_amdgcn_s_setprio(1);
    pvslice(s0, 0, 0);
    pvslice(s0, 8, 1);
    pvslice(s1, 0, 2);
    pvslice(s1, 8, 3);
    __builtin_amdgcn_s_setprio(0);

    __builtin_amdgcn_s_barrier();
    asm volatile("" ::: "memory");
    cur ^= 1;
  }

  // ---- write partials (unnormalized acc + per-row m,l) ----
#pragma unroll
  for (int db = 0; db < 4; ++db)
#pragma unroll
    for (int r = 0; r < 16; ++r) {
      const int qr = qrow0w + (r & 3) + 8 * (r >> 2) + 4 * hi;
      pacc[((size_t)ch * N_P + qr) * 128 + db * 32 + c32] = acc[db][r];
    }
  if (hi == 0) {
    const int qr = qrow0w + c32;
    pml[((size_t)ch * N_P + qr) * 2]     = m;
    pml[((size_t)ch * N_P + qr) * 2 + 1] = lsum;
  }
}

// ---------------------------------------------------------------------------
// combine chunk partials -> social context bf16 into PH2[:,128:256]
// ---------------------------------------------------------------------------
__global__ __launch_bounds__(256) void combine_kernel(const float* __restrict__ pacc,
                                                      const float* __restrict__ pml,
                                                      short* __restrict__ PH2) {
  int tid = threadIdx.x;
  int row = blockIdx.x * 2 + (tid >> 7);
  int d = tid & 127;
  float mv[8], lv[8], M = -1e30f;
#pragma unroll
  for (int cc = 0; cc < 8; ++cc) {
    mv[cc] = pml[(cc * N_P + row) * 2];
    lv[cc] = pml[(cc * N_P + row) * 2 + 1];
    M = fmaxf(M, mv[cc]);
  }
  float L = 0.f, O = 0.f;
#pragma unroll
  for (int cc = 0; cc < 8; ++cc) {
    float w = exp2f(mv[cc] - M);
    L += lv[cc] * w;
    O += pacc[((size_t)cc * N_P + row) * 128 + d] * w;
  }
  PH2[row * 256 + 128 + d] = f2bf(O / L);
}

// ---------------------------------------------------------------------------
// GRU gates + d = (1-z)(ng-h) + LayerNorm. One wave per row.
// ---------------------------------------------------------------------------
__global__ __launch_bounds__(256) void final_kernel(const float* __restrict__ gx,
                                                    const float* __restrict__ gh,
                                                    const float* __restrict__ ph,
                                                    const float* __restrict__ gamma,
                                                    const float* __restrict__ beta,
                                                    float* __restrict__ out) {
  int tid = threadIdx.x, wid = tid >> 6, l = tid & 63;
  int row = blockIdx.x * 4 + wid;
  float dd[2];
#pragma unroll
  for (int half = 0; half < 2; ++half) {
    int d = l + 64 * half;
    float h = ph[row * 128 + d];
    float xr = gx[row * 384 + d], hr = gh[row * 384 + d];
    float xz = gx[row * 384 + 128 + d], hz = gh[row * 384 + 128 + d];
    float xn = gx[row * 384 + 256 + d], hn = gh[row * 384 + 256 + d];
    float r = 1.f / (1.f + exp2f(-LOG2E * (xr + hr)));
    float z = 1.f / (1.f + exp2f(-LOG2E * (xz + hz)));
    float a = xn + r * hn;
    float ng = 1.f - 2.f / (1.f + exp2f(2.f * LOG2E * a));  // tanh(a)
    dd[half] = (1.f - z) * (ng - h);
  }
  float s = dd[0] + dd[1], ss = dd[0] * dd[0] + dd[1] * dd[1];
#pragma unroll
  for (int mk = 1; mk < 64; mk <<= 1) {
    s += __shfl_xor(s, mk);
    ss += __shfl_xor(ss, mk);
  }
  float mu = s * (1.f / 128.f);
  float var = ss * (1.f / 128.f) - mu * mu;
  float rs = rsqrtf(var + 1e-5f);
#pragma unroll
  for (int half = 0; half < 2; ++half) {
    int d = l + 64 * half;
    out[row * 128 + d] = (dd[half] - mu) * rs * gamma[d] + beta[d];
  }
}

// ---------------------------------------------------------------------------
extern "C" void kernel_launch(void* const* d_in, const int* in_sizes, int n_in,
                              void* d_out, int out_size, void* d_ws, size_t ws_size,
                              hipStream_t stream) {
  const float* t       = (const float*)d_in[0];
  const float* ph      = (const float*)d_in[1];
  const float* E       = (const float*)d_in[2];
  const float* W_time  = (const float*)d_in[3];
  const float* b_time  = (const float*)d_in[4];
  const float* W_loc   = (const float*)d_in[5];
  const float* b_loc   = (const float*)d_in[6];
  const float* Wq      = (const float*)d_in[7];
  const float* bq      = (const float*)d_in[8];
  const float* Wk      = (const float*)d_in[9];
  const float* bk      = (const float*)d_in[10];
  const float* Wv      = (const float*)d_in[11];
  const float* bv      = (const float*)d_in[12];
  const float* W_merge = (const float*)d_in[13];
  const float* b_merge = (const float*)d_in[14];
  const float* W_ih    = (const float*)d_in[15];
  const float* b_ih    = (const float*)d_in[16];
  const float* W_hh    = (const float*)d_in[17];
  const float* b_hh    = (const float*)d_in[18];
  const float* gamma   = (const float*)d_in[19];
  const float* beta    = (const float*)d_in[20];
  float* out = (float*)d_out;

  char* w = (char*)d_ws;
  auto alloc = [&](size_t bytes) {
    char* p = w;
    w += (bytes + 255) & ~(size_t)255;
    return p;
  };
  short* W1    = (short*)alloc(896 * 128 * 2);
  float* bias1 = (float*)alloc(896 * 4);
  short* Wmrg  = (short*)alloc(128 * 256 * 2);
  short* Wih   = (short*)alloc(384 * 256 * 2);
  float* tctx  = (float*)alloc(32 * 4);
  short* PH2   = (short*)alloc((size_t)N_P * 256 * 2);
  short* X3    = (short*)alloc((size_t)N_P * 256 * 2);
  short* qbuf  = (short*)alloc((size_t)N_P * 128 * 2);
  short* kbuf  = (short*)alloc((size_t)N_P * 128 * 2);
  float* vf    = (float*)alloc((size_t)N_P * 128 * 4);
  short* vT    = (short*)alloc((size_t)128 * N_P * 2);
  float* locf  = (float*)alloc((size_t)N_P * 112 * 4);
  float* ghf   = (float*)alloc((size_t)N_P * 384 * 4);
  float* gx    = (float*)alloc((size_t)N_P * 384 * 4);
  float* pacc  = (float*)alloc((size_t)NCHNK * N_P * 128 * 4);
  float* pml   = (float*)alloc((size_t)NCHNK * N_P * 2 * 4);

  pack2_kernel<<<64, 256, 0, stream>>>(t, W_time, b_time, W_loc, b_loc, Wq, bq, Wk, bk,
                                       Wv, bv, W_merge, W_ih, W_hh, b_hh,
                                       W1, bias1, Wmrg, Wih, tctx);
  prep_kernel<<<1024, 256, 0, stream>>>(ph, tctx, PH2, X3);
  gemm_kernel<0, 128><<<dim3(128, 14), 256, 0, stream>>>(
      PH2, 256, W1, bias1, qbuf, kbuf, vf, locf, ghf, nullptr, nullptr);
  transpose_v<<<dim3(256, 4), dim3(32, 8), 0, stream>>>(vf, vT);
  spatial_kernel<<<2048, 256, 0, stream>>>(locf, E, X3);
  attn_kernel<<<256, 512, 0, stream>>>(qbuf, kbuf, vT, pacc, pml);
  combine_kernel<<<4096, 256, 0, stream>>>(pacc, pml, PH2);
  gemm_kernel<1, 256><<<dim3(128, 2), 256, 0, stream>>>(
      PH2, 256, Wmrg, b_merge, nullptr, nullptr, nullptr, nullptr, nullptr, X3, nullptr);
  gemm_kernel<2, 256><<<dim3(128, 6), 256, 0, stream>>>(
      X3, 256, Wih, b_ih, nullptr, nullptr, nullptr, nullptr, nullptr, nullptr, gx);
  final_kernel<<<2048, 256, 0, stream>>>(gx, ghf, ph, gamma, beta, out);
}

// Round 3
// 110.439 us; speedup vs baseline: 1.8112x; 1.1362x over previous
//
#include <hip/hip_runtime.h>

// ---------------------------------------------------------------------------
// HouseholdODEFunc: soft-location context + leave-one-out attention + GRU + LN
// N=8192 people, H=128. All heavy matmuls in bf16 MFMA, fp32 accum.
// Attention: m214-style 8-wave 32x32 flash kernel, swapped QK^T, in-register
// softmax (cvt_pk + permlane32_swap), defer-max, global_load_lds staging.
// This round: bf16 partials, merge-GEMM folded into GRU-input GEMM via
// precomputed W_all = [Wih[:,:128]@W_merge | Wih[:,128:224] | 0], 128^2 GEMM
// tiles with async staging, fused dispatches (7 total).
// ---------------------------------------------------------------------------

typedef __attribute__((ext_vector_type(8)))  short bf16x8;
typedef __attribute__((ext_vector_type(4)))  float f32x4;
typedef __attribute__((ext_vector_type(16))) float f32x16;
typedef __attribute__((ext_vector_type(4)))  unsigned uint4v;

#define N_P   8192
#define H_D   128
#define NCHNK 8
#define CHLEN (N_P / NCHNK)    // 1024 kv per chunk
#define KVB   64
#define NTIL  (CHLEN / KVB)    // 16 tiles per chunk
#define LDE   384              // PH2e row stride: ph(128)|social(128)|spatial(64)|time(32)|pad(32)

__device__ __forceinline__ short f2bf(float f) {   // RNE float->bf16 bits
  unsigned u = __float_as_uint(f);
  u = (u + 0x7fffu + ((u >> 16) & 1u)) >> 16;
  return (short)u;
}
__device__ __forceinline__ float bf2f(short s) {
  return __uint_as_float(((unsigned)(unsigned short)s) << 16);
}

// XOR-swizzled byte offset of a 16B slot in a row-major LDS tile.
__device__ __forceinline__ int swzb(int row, int slot, int nslots) {
  return (row * nslots + (slot ^ (row & ((nslots - 1) & 7)))) << 4;
}

__device__ __forceinline__ unsigned cvtpk(float a, float b) {
  unsigned d;
  asm("v_cvt_pk_bf16_f32 %0, %1, %2" : "=v"(d) : "v"(a), "v"(b));
  return d;
}

__device__ __forceinline__ void swap32(unsigned& a, unsigned& b) {
#if __has_builtin(__builtin_amdgcn_permlane32_swap)
  auto r = __builtin_amdgcn_permlane32_swap(a, b, false, false);
  a = r[0]; b = r[1];
#else
  asm volatile("v_permlane32_swap_b32 %0, %1" : "+v"(a), "+v"(b));
#endif
}

typedef __attribute__((address_space(1))) const void GV;
typedef __attribute__((address_space(3))) void LV;
__device__ __forceinline__ void gld_lds16(const void* g, void* l) {
  __builtin_amdgcn_global_load_lds((GV*)g, (LV*)l, 16, 0, 0);
}

__constant__ const float QSCALE = 0.12751551485988857f; // log2(e)/sqrt(128)
#define LOG2E 1.4426950408889634f

// ---------------------------------------------------------------------------
// init: weight pack (W1,bias1) + W_all/bias_gx fold + PH2e prep (ph/time/pad)
// blocks [0,64): pack; [64,448): W_all row per WG; [448,1472): prep
// ---------------------------------------------------------------------------
__global__ __launch_bounds__(256) void init_kernel(
    const float* t, const float* W_time, const float* b_time,
    const float* W_loc, const float* b_loc,
    const float* Wq, const float* bq, const float* Wk, const float* bk,
    const float* Wv, const float* bv,
    const float* W_merge, const float* b_merge,
    const float* W_ih, const float* b_ih,
    const float* W_hh, const float* b_hh,
    const float* ph,
    short* W1, float* bias1, short* W_all, float* bias_gx, short* PH2e) {
  const int b = blockIdx.x, tidl = threadIdx.x;
  if (b < 64) {
    int tid = b * 256 + tidl, stride = 64 * 256;
    for (int i = tid; i < 896 * 128; i += stride) {
      int r = i >> 7, k = i & 127;
      float v;
      if (r < 128)      v = Wq[r * 128 + k];
      else if (r < 256) v = Wk[(r - 128) * 128 + k];
      else if (r < 384) v = Wv[(r - 256) * 128 + k];
      else if (r < 484) v = W_loc[(r - 384) * 128 + k];
      else if (r < 868) v = W_hh[(r - 484) * 128 + k];
      else              v = 0.f;
      W1[i] = f2bf(v);
    }
    for (int i = tid; i < 896; i += stride) {
      float v;
      if (i < 128)      v = bq[i];
      else if (i < 256) v = bk[i - 128];
      else if (i < 384) v = bv[i - 256];
      else if (i < 484) v = b_loc[i - 384];
      else if (i < 868) v = b_hh[i - 484];
      else              v = 0.f;
      bias1[i] = v;
    }
  } else if (b < 448) {
    // one WG per output row n of W_all: W_all[n][k<256] = Wih[n,:128]@W_merge[:,k]
    __shared__ float rowj[128];
    const int n = b - 64;
    if (tidl < 128) rowj[tidl] = W_ih[n * 224 + tidl];
    __syncthreads();
    {
      float acc = 0.f;
#pragma unroll 8
      for (int j = 0; j < 128; ++j) acc += rowj[j] * W_merge[j * 256 + tidl];
      W_all[n * 384 + tidl] = f2bf(acc);
    }
    if (tidl < 128) {
      int k2 = 256 + tidl;
      float v;
      if (k2 < 320)      v = W_ih[n * 224 + 128 + (k2 - 256)];   // spatial cols
      else if (k2 < 352) v = W_ih[n * 224 + 192 + (k2 - 320)];   // time cols
      else               v = 0.f;                                 // pad
      W_all[n * 384 + k2] = f2bf(v);
    }
    if (tidl < 64) {
      float p = rowj[tidl] * b_merge[tidl] + rowj[tidl + 64] * b_merge[tidl + 64];
#pragma unroll
      for (int mk = 1; mk < 64; mk <<= 1) p += __shfl_xor(p, mk);
      if (tidl == 0) bias_gx[n] = b_ih[n] + p;
    }
  } else {
    int tid = (b - 448) * 256 + tidl, stride = 1024 * 256;
    for (int i = tid; i < N_P * H_D; i += stride) {
      int r = i >> 7, d = i & 127;
      PH2e[r * LDE + d] = f2bf(ph[i]);
    }
    const float t0 = t[0];
    for (int i = tid; i < N_P * 64; i += stride) {
      int r = i >> 6, j = i & 63;
      float v = (j < 32) ? (t0 * W_time[j] + b_time[j]) : 0.f;
      PH2e[r * LDE + 320 + j] = f2bf(v);
    }
  }
}

// ---------------------------------------------------------------------------
// 128x128-tile MFMA GEMM: C[M,N] = X[M,K](bf16, stride ldx) @ W[N,K]^T + bias
// 4 waves (2x2), each 64x64 (4x4 16x16 frags). global_load_lds staging with
// pre-swizzled source (linear LDS dst, swizzled read).
// MODE 0: fused QKV/loc/gh epilogue (gemm0). MODE 2: gx fp32 (gemmG).
// ---------------------------------------------------------------------------
template <int MODE, int K>
__global__ __launch_bounds__(256, 2) void gemm128_kernel(
    const short* __restrict__ X, int ldx, const short* __restrict__ W,
    const float* __restrict__ bias,
    short* out_q, short* out_k, float* out_v, float* out_loc, float* out_gh,
    float* out_gx) {
  __shared__ short Xl[128 * 128];
  __shared__ short Wl[128 * 128];
  const int tid = threadIdx.x;
  const int bm = blockIdx.x * 128, bn = blockIdx.y * 128;
  const int l = tid & 63, wid = tid >> 6;
  const int g = l >> 4, c = l & 15;
  const int wr = wid >> 1, wc = wid & 1;
  f32x4 acc[4][4] = {};
  constexpr int KT = K / 128;
#pragma unroll 1
  for (int kt = 0; kt < KT; ++kt) {
    const int k0 = kt * 128;
#pragma unroll
    for (int pass = 0; pass < 8; ++pass) {
      int s = tid + pass * 256;            // 0..2047
      int row = s >> 4, p = s & 15;
      int lsl = p ^ (row & 7);             // pre-swizzled source slot
      gld_lds16(X + (size_t)(bm + row) * ldx + k0 + lsl * 8, (char*)Xl + s * 16);
    }
#pragma unroll
    for (int pass = 0; pass < 8; ++pass) {
      int s = tid + pass * 256;
      int row = s >> 4, p = s & 15;
      int lsl = p ^ (row & 7);
      gld_lds16(W + (size_t)(bn + row) * K + k0 + lsl * 8, (char*)Wl + s * 16);
    }
    __syncthreads();
#pragma unroll
    for (int kc = 0; kc < 4; ++kc) {
      bf16x8 a[4], bfr[4];
#pragma unroll
      for (int mi = 0; mi < 4; ++mi)
        a[mi] = *(const bf16x8*)((const char*)Xl + swzb(wr * 64 + mi * 16 + c, kc * 4 + g, 16));
#pragma unroll
      for (int ni = 0; ni < 4; ++ni)
        bfr[ni] = *(const bf16x8*)((const char*)Wl + swzb(wc * 64 + ni * 16 + c, kc * 4 + g, 16));
#pragma unroll
      for (int mi = 0; mi < 4; ++mi)
#pragma unroll
        for (int ni = 0; ni < 4; ++ni)
          acc[mi][ni] = __builtin_amdgcn_mfma_f32_16x16x32_bf16(a[mi], bfr[ni], acc[mi][ni], 0, 0, 0);
    }
    if (kt + 1 < KT) __syncthreads();
  }
#pragma unroll
  for (int mi = 0; mi < 4; ++mi)
#pragma unroll
    for (int ni = 0; ni < 4; ++ni)
#pragma unroll
      for (int r = 0; r < 4; ++r) {
        int row = bm + wr * 64 + mi * 16 + 4 * g + r;
        int col = bn + wc * 64 + ni * 16 + c;
        float val = acc[mi][ni][r] + bias[col];
        if constexpr (MODE == 0) {
          if (col < 128)      out_q[row * 128 + col] = f2bf(val * QSCALE);
          else if (col < 256) out_k[row * 128 + col - 128] = f2bf(val);
          else if (col < 384) out_v[row * 128 + col - 256] = val;
          else if (col < 484) out_loc[row * 112 + col - 384] = val;
          else if (col < 868) out_gh[row * 384 + col - 484] = val;
        } else {
          out_gx[row * 384 + col] = val;
        }
      }
}

// ---------------------------------------------------------------------------
// fused: blocks [0,1024) v fp32 -> vT bf16 transpose; [1024,3072) zone softmax
// + spatial context into PH2e cols 256..319
// ---------------------------------------------------------------------------
__global__ __launch_bounds__(256) void tv_spatial_kernel(const float* __restrict__ vf,
                                                         short* __restrict__ vT,
                                                         const float* __restrict__ locf,
                                                         const float* __restrict__ E,
                                                         short* __restrict__ PH2e) {
  const int b = blockIdx.x, tid = threadIdx.x;
  if (b < 1024) {
    __shared__ float T[32][33];
    int tx = tid & 31, ty = tid >> 5;          // ty in 0..7
    int bi = b >> 2, bd = b & 3;
#pragma unroll
    for (int k = 0; k < 4; ++k)
      T[ty + 8 * k][tx] = vf[(bi * 32 + ty + 8 * k) * 128 + bd * 32 + tx];
    __syncthreads();
#pragma unroll
    for (int k = 0; k < 4; ++k)
      vT[(size_t)(bd * 32 + ty + 8 * k) * N_P + bi * 32 + tx] = f2bf(T[tx][ty + 8 * k]);
  } else {
    __shared__ float pl[4][104];
    int wid = tid >> 6, l = tid & 63;
    int row = (b - 1024) * 4 + wid;
    float v0 = locf[row * 112 + l];
    float v1 = (l + 64 < 100) ? locf[row * 112 + 64 + l] : -1e30f;
    float m = fmaxf(v0, v1);
#pragma unroll
    for (int mk = 1; mk < 64; mk <<= 1) m = fmaxf(m, __shfl_xor(m, mk));
    float p0 = exp2f((v0 - m) * LOG2E);
    float p1 = (l + 64 < 100) ? exp2f((v1 - m) * LOG2E) : 0.f;
    float s = p0 + p1;
#pragma unroll
    for (int mk = 1; mk < 64; mk <<= 1) s += __shfl_xor(s, mk);
    float inv = 1.f / s;
    pl[wid][l] = p0 * inv;
    if (l + 64 < 100) pl[wid][64 + l] = p1 * inv;
    float acc = 0.f;
#pragma unroll 4
    for (int z = 0; z < 100; ++z) acc += pl[wid][z] * E[z * 64 + l];
    PH2e[row * LDE + 256 + l] = f2bf(acc);
  }
}

// ---------------------------------------------------------------------------
// Flash attention, m214 structure. Grid: 32 q-blocks x 8 kv-chunks = 256 WGs.
// ---------------------------------------------------------------------------
__global__ __launch_bounds__(512, 2) void attn_kernel(
    const short* __restrict__ qb, const short* __restrict__ kb,
    const short* __restrict__ vT, short* __restrict__ pacc,
    float* __restrict__ pml) {
  __shared__ short Kl[2][KVB * H_D];     // [64 kv][128 d], swizzled, 16KB each
  __shared__ short Vl[2][H_D * KVB];     // [128 d][64 kv], swizzled, 16KB each
  const int tid = threadIdx.x;
  const int qbk = blockIdx.x >> 3, ch = blockIdx.x & 7;
  const int chbase = ch * CHLEN;
  const int l = tid & 63, wid = tid >> 6;
  const int c32 = l & 31, hi = l >> 5;
  const int qrow0w = qbk * 256 + wid * 32;

  const int i0 = tid, i1 = tid + 512;
  const int kr0 = i0 >> 4, ks0 = (i0 & 15) ^ (kr0 & 7);
  const int kr1 = i1 >> 4, ks1 = (i1 & 15) ^ (kr1 & 7);
  const int vr0 = i0 >> 3, vs0 = (i0 & 7) ^ (vr0 & 7);
  const int vr1 = i1 >> 3, vs1 = (i1 & 7) ^ (vr1 & 7);
  const short* kA0 = kb + kr0 * 128 + ks0 * 8 + (size_t)chbase * 128;
  const short* kA1 = kb + kr1 * 128 + ks1 * 8 + (size_t)chbase * 128;
  const short* vA0 = vT + (size_t)vr0 * N_P + vs0 * 8 + chbase;
  const short* vA1 = vT + (size_t)vr1 * N_P + vs1 * 8 + chbase;
  char* ldsK = (char*)&Kl[0][0];
  char* ldsV = (char*)&Vl[0][0];

  auto stage = [&](int b, int tt) {
    const int off = tt * KVB;
    gld_lds16(kA0 + (size_t)off * 128, ldsK + b * 16384 + i0 * 16);
    gld_lds16(kA1 + (size_t)off * 128, ldsK + b * 16384 + i1 * 16);
    gld_lds16(vA0 + off,               ldsV + b * 16384 + i0 * 16);
    gld_lds16(vA1 + off,               ldsV + b * 16384 + i1 * 16);
  };

  bf16x8 qf[8];
#pragma unroll
  for (int sl = 0; sl < 8; ++sl)
    qf[sl] = *(const bf16x8*)(qb + (size_t)(qrow0w + c32) * 128 + sl * 16 + hi * 8);

  f32x16 acc[4] = {};
  float m = -1e30f, lsum = 0.f;

  stage(0, 0);
  int cur = 0;

  for (int t = 0; t < NTIL; ++t) {
    if (t + 1 < NTIL) {
      stage(cur ^ 1, t + 1);
      asm volatile("s_waitcnt vmcnt(4)" ::: "memory");
    } else {
      asm volatile("s_waitcnt vmcnt(0)" ::: "memory");
    }
    __builtin_amdgcn_s_barrier();
    asm volatile("" ::: "memory");

    const int kv0 = chbase + t * KVB;
    const char* Kb = (const char*)&Kl[cur][0];
    const char* Vb = (const char*)&Vl[cur][0];

    f32x16 s0 = {}, s1 = {};
    __builtin_amdgcn_s_setprio(1);
#pragma unroll
    for (int sl = 0; sl < 8; ++sl) {
      bf16x8 k0 = *(const bf16x8*)(Kb + swzb(c32, 2 * sl + hi, 16));
      bf16x8 k1 = *(const bf16x8*)(Kb + swzb(32 + c32, 2 * sl + hi, 16));
      s0 = __builtin_amdgcn_mfma_f32_32x32x16_bf16(k0, qf[sl], s0, 0, 0, 0);
      s1 = __builtin_amdgcn_mfma_f32_32x32x16_bf16(k1, qf[sl], s1, 0, 0, 0);
    }
    __builtin_amdgcn_s_setprio(0);

    if (qrow0w + 32 > kv0 && qrow0w < kv0 + 64) {
      const int qr = qrow0w + c32;
#pragma unroll
      for (int r = 0; r < 16; ++r) {
        const int rowp = (r & 3) + 8 * (r >> 2) + 4 * hi;
        s0[r] = (kv0 + rowp == qr) ? -1e30f : s0[r];
        s1[r] = (kv0 + 32 + rowp == qr) ? -1e30f : s1[r];
      }
    }

    f32x16 mx;
#pragma unroll
    for (int r = 0; r < 16; ++r) mx[r] = fmaxf(s0[r], s1[r]);
#pragma unroll
    for (int w2 = 8; w2 >= 1; w2 >>= 1)
#pragma unroll
      for (int r = 0; r < w2; ++r) mx[r] = fmaxf(mx[r], mx[r + w2]);
    float pm = fmaxf(mx[0], __shfl_xor(mx[0], 32));

    if (__any(pm > m + 8.f)) {
      float mn = fmaxf(m, pm);
      float corr = exp2f(m - mn);
      m = mn;
      lsum *= corr;
#pragma unroll
      for (int r = 0; r < 16; ++r) {
        float cr = __shfl(corr, (r & 3) + 8 * (r >> 2) + 4 * hi);
        acc[0][r] *= cr; acc[1][r] *= cr; acc[2][r] *= cr; acc[3][r] *= cr;
      }
    }
    float tsa = 0.f, tsb = 0.f;
#pragma unroll
    for (int r = 0; r < 16; ++r) { s0[r] = exp2f(s0[r] - m); tsa += s0[r]; }
#pragma unroll
    for (int r = 0; r < 16; ++r) { s1[r] = exp2f(s1[r] - m); tsb += s1[r]; }
    float ts = tsa + tsb;
    ts += __shfl_xor(ts, 32);
    lsum += ts;

    auto pvslice = [&](const f32x16& ss, int base, int sl4) {
      unsigned dA = cvtpk(ss[base + 0], ss[base + 1]);
      unsigned dB = cvtpk(ss[base + 2], ss[base + 3]);
      unsigned dC = cvtpk(ss[base + 4], ss[base + 5]);
      unsigned dD = cvtpk(ss[base + 6], ss[base + 7]);
      swap32(dA, dC);
      swap32(dB, dD);
      uint4v w = {dA, dB, dC, dD};
      bf16x8 pa = __builtin_bit_cast(bf16x8, w);
#pragma unroll
      for (int db = 0; db < 4; ++db) {
        bf16x8 vf = *(const bf16x8*)(Vb + swzb(db * 32 + c32, 2 * sl4 + hi, 8));
        acc[db] = __builtin_amdgcn_mfma_f32_32x32x16_bf16(pa, vf, acc[db], 0, 0, 0);
      }
    };
    __builtin_amdgcn_s_setprio(1);
    pvslice(s0, 0, 0);
    pvslice(s0, 8, 1);
    pvslice(s1, 0, 2);
    pvslice(s1, 8, 3);
    __builtin_amdgcn_s_setprio(0);

    __builtin_amdgcn_s_barrier();
    asm volatile("" ::: "memory");
    cur ^= 1;
  }

#pragma unroll
  for (int db = 0; db < 4; ++db)
#pragma unroll
    for (int r = 0; r < 16; ++r) {
      const int qr = qrow0w + (r & 3) + 8 * (r >> 2) + 4 * hi;
      pacc[((size_t)ch * N_P + qr) * 128 + db * 32 + c32] = f2bf(acc[db][r]);
    }
  if (hi == 0) {
    const int qr = qrow0w + c32;
    pml[((size_t)ch * N_P + qr) * 2]     = m;
    pml[((size_t)ch * N_P + qr) * 2 + 1] = lsum;
  }
}

// ---------------------------------------------------------------------------
// combine chunk partials -> social context bf16 into PH2e cols 128..255
// ---------------------------------------------------------------------------
__global__ __launch_bounds__(256) void combine_kernel(const short* __restrict__ pacc,
                                                      const float* __restrict__ pml,
                                                      short* __restrict__ PH2e) {
  int tid = threadIdx.x;
  int row = blockIdx.x * 2 + (tid >> 7);
  int d = tid & 127;
  float mv[8], lv[8], M = -1e30f;
#pragma unroll
  for (int cc = 0; cc < 8; ++cc) {
    mv[cc] = pml[(cc * N_P + row) * 2];
    lv[cc] = pml[(cc * N_P + row) * 2 + 1];
    M = fmaxf(M, mv[cc]);
  }
  float L = 0.f, O = 0.f;
#pragma unroll
  for (int cc = 0; cc < 8; ++cc) {
    float w = exp2f(mv[cc] - M);
    L += lv[cc] * w;
    O += bf2f(pacc[((size_t)cc * N_P + row) * 128 + d]) * w;
  }
  PH2e[row * LDE + 128 + d] = f2bf(O / L);
}

// ---------------------------------------------------------------------------
// GRU gates + d = (1-z)(ng-h) + LayerNorm. One wave per row.
// ---------------------------------------------------------------------------
__global__ __launch_bounds__(256) void final_kernel(const float* __restrict__ gx,
                                                    const float* __restrict__ gh,
                                                    const float* __restrict__ ph,
                                                    const float* __restrict__ gamma,
                                                    const float* __restrict__ beta,
                                                    float* __restrict__ out) {
  int tid = threadIdx.x, wid = tid >> 6, l = tid & 63;
  int row = blockIdx.x * 4 + wid;
  float dd[2];
#pragma unroll
  for (int half = 0; half < 2; ++half) {
    int d = l + 64 * half;
    float h = ph[row * 128 + d];
    float xr = gx[row * 384 + d], hr = gh[row * 384 + d];
    float xz = gx[row * 384 + 128 + d], hz = gh[row * 384 + 128 + d];
    float xn = gx[row * 384 + 256 + d], hn = gh[row * 384 + 256 + d];
    float r = 1.f / (1.f + exp2f(-LOG2E * (xr + hr)));
    float z = 1.f / (1.f + exp2f(-LOG2E * (xz + hz)));
    float a = xn + r * hn;
    float ng = 1.f - 2.f / (1.f + exp2f(2.f * LOG2E * a));  // tanh(a)
    dd[half] = (1.f - z) * (ng - h);
  }
  float s = dd[0] + dd[1], ss = dd[0] * dd[0] + dd[1] * dd[1];
#pragma unroll
  for (int mk = 1; mk < 64; mk <<= 1) {
    s += __shfl_xor(s, mk);
    ss += __shfl_xor(ss, mk);
  }
  float mu = s * (1.f / 128.f);
  float var = ss * (1.f / 128.f) - mu * mu;
  float rs = rsqrtf(var + 1e-5f);
#pragma unroll
  for (int half = 0; half < 2; ++half) {
    int d = l + 64 * half;
    out[row * 128 + d] = (dd[half] - mu) * rs * gamma[d] + beta[d];
  }
}

// ---------------------------------------------------------------------------
extern "C" void kernel_launch(void* const* d_in, const int* in_sizes, int n_in,
                              void* d_out, int out_size, void* d_ws, size_t ws_size,
                              hipStream_t stream) {
  const float* t       = (const float*)d_in[0];
  const float* ph      = (const float*)d_in[1];
  const float* E       = (const float*)d_in[2];
  const float* W_time  = (const float*)d_in[3];
  const float* b_time  = (const float*)d_in[4];
  const float* W_loc   = (const float*)d_in[5];
  const float* b_loc   = (const float*)d_in[6];
  const float* Wq      = (const float*)d_in[7];
  const float* bq      = (const float*)d_in[8];
  const float* Wk      = (const float*)d_in[9];
  const float* bk      = (const float*)d_in[10];
  const float* Wv      = (const float*)d_in[11];
  const float* bv      = (const float*)d_in[12];
  const float* W_merge = (const float*)d_in[13];
  const float* b_merge = (const float*)d_in[14];
  const float* W_ih    = (const float*)d_in[15];
  const float* b_ih    = (const float*)d_in[16];
  const float* W_hh    = (const float*)d_in[17];
  const float* b_hh    = (const float*)d_in[18];
  const float* gamma   = (const float*)d_in[19];
  const float* beta    = (const float*)d_in[20];
  float* out = (float*)d_out;

  char* w = (char*)d_ws;
  auto alloc = [&](size_t bytes) {
    char* p = w;
    w += (bytes + 255) & ~(size_t)255;
    return p;
  };
  short* W1     = (short*)alloc(896 * 128 * 2);
  float* bias1  = (float*)alloc(896 * 4);
  short* W_all  = (short*)alloc(384 * 384 * 2);
  float* bias_gx= (float*)alloc(384 * 4);
  short* PH2e   = (short*)alloc((size_t)N_P * LDE * 2);
  short* qbuf   = (short*)alloc((size_t)N_P * 128 * 2);
  short* kbuf   = (short*)alloc((size_t)N_P * 128 * 2);
  float* vf     = (float*)alloc((size_t)N_P * 128 * 4);
  short* vT     = (short*)alloc((size_t)128 * N_P * 2);
  float* locf   = (float*)alloc((size_t)N_P * 112 * 4);
  float* ghf    = (float*)alloc((size_t)N_P * 384 * 4);
  float* gx     = (float*)alloc((size_t)N_P * 384 * 4);
  short* pacc   = (short*)alloc((size_t)NCHNK * N_P * 128 * 2);
  float* pml    = (float*)alloc((size_t)NCHNK * N_P * 2 * 4);

  init_kernel<<<1472, 256, 0, stream>>>(t, W_time, b_time, W_loc, b_loc, Wq, bq,
                                        Wk, bk, Wv, bv, W_merge, b_merge,
                                        W_ih, b_ih, W_hh, b_hh, ph,
                                        W1, bias1, W_all, bias_gx, PH2e);
  gemm128_kernel<0, 128><<<dim3(64, 7), 256, 0, stream>>>(
      PH2e, LDE, W1, bias1, qbuf, kbuf, vf, locf, ghf, nullptr);
  tv_spatial_kernel<<<3072, 256, 0, stream>>>(vf, vT, locf, E, PH2e);
  attn_kernel<<<256, 512, 0, stream>>>(qbuf, kbuf, vT, pacc, pml);
  combine_kernel<<<4096, 256, 0, stream>>>(pacc, pml, PH2e);
  gemm128_kernel<2, 384><<<dim3(64, 3), 256, 0, stream>>>(
      PH2e, LDE, W_all, bias_gx, nullptr, nullptr, nullptr, nullptr, nullptr, gx);
  final_kernel<<<2048, 256, 0, stream>>>(gx, ghf, ph, gamma, beta, out);
}